// Round 8
// baseline (2481.611 us; speedup 1.0000x reference)
//
#include <hip/hip_runtime.h>
#include <math.h>

#define B_  64
#define H_  64
#define W_  64
#define HW  4096   // H_*W_
#define NPIX 262144.0f  // B_*HW

typedef __fp16 h2 __attribute__((ext_vector_type(2)));

// ---------------------------------------------------------------------------
// Weight pack: w[O][C*9] (K idx = c*9+t) -> wp[(t*(C/2)+c/2)*O+o] = h2(w_c, w_c+1)
// K reordered tap-major so channel pairs are f16x2 lanes for v_dot2_f32_f16.
// ---------------------------------------------------------------------------
__global__ __launch_bounds__(256) void wpack_k(
    const float* __restrict__ w, h2* __restrict__ wp, int O, int C)
{
    const int i = blockIdx.x * 256 + threadIdx.x;
    const int total = 9 * (C / 2) * O;
    if (i < total) {
        const int o    = i % O;
        const int rest = i / O;
        const int cp   = rest % (C / 2);
        const int t    = rest / (C / 2);
        const int c    = 2 * cp;
        h2 p;
        p.x = (__fp16)w[o * (C * 9) + c * 9 + t];
        p.y = (__fp16)w[o * (C * 9) + (c + 1) * 9 + t];
        wp[i] = p;
    }
}

// ---------------------------------------------------------------------------
// Fused per-block BN stats accumulation (sum, sumsq per channel).
// ---------------------------------------------------------------------------
template<int CT>
__device__ __forceinline__ void stats_accum(
    const float* res, float* sacc, float* ls, int tid)
{
    if (tid < 2 * CT) ls[tid] = 0.f;
    __syncthreads();
#pragma unroll
    for (int o = 0; o < CT; ++o) {
        float s = res[o], s2 = res[o] * res[o];
        for (int off = 32; off; off >>= 1) {
            s  += __shfl_down(s,  off);
            s2 += __shfl_down(s2, off);
        }
        if ((tid & 63) == 0) {
            atomicAdd(&ls[2 * o],     s);
            atomicAdd(&ls[2 * o + 1], s2);
        }
    }
    __syncthreads();
    if (tid < 2 * CT) atomicAdd(&sacc[tid], ls[tid]);
}

// ---------------------------------------------------------------------------
// BN finalize: sums -> mean/rstd.
// ---------------------------------------------------------------------------
template<int C>
__global__ __launch_bounds__(64) void bn_fin_k(
    const float* __restrict__ sacc, float* __restrict__ st)
{
    const int t = threadIdx.x;
    if (t < C) {
        const float mean = sacc[2 * t] / NPIX;
        const float var  = sacc[2 * t + 1] / NPIX - mean * mean;
        st[t]     = mean;
        st[C + t] = rsqrtf(var + 1e-5f);
    }
}

// ---------------------------------------------------------------------------
// conv1: 3x3 conv (3->8) + ReLU, NCHW in/out, fused stats. (small; fp32)
// ---------------------------------------------------------------------------
__global__ __launch_bounds__(256) void conv1_k(
    const float* __restrict__ x, const float* __restrict__ w,
    float* __restrict__ out, float* __restrict__ sacc)
{
    const int tid = threadIdx.x;
    const int pix = blockIdx.x * 256 + tid;
    const int b   = blockIdx.y;
    const int h   = pix >> 6, ww = pix & 63;

    float acc[8];
#pragma unroll
    for (int o = 0; o < 8; ++o) acc[o] = 0.f;

#pragma unroll
    for (int ci = 0; ci < 3; ++ci) {
        const float* xp = x + ((size_t)b * 3 + ci) * HW;
#pragma unroll
        for (int t = 0; t < 9; ++t) {
            const int yy = h + t / 3 - 1, xx = ww + t % 3 - 1;
            const bool ok = (yy >= 0) && (yy < 64) && (xx >= 0) && (xx < 64);
            const float xv = ok ? xp[min(max(yy,0),63) * 64 + min(max(xx,0),63)] : 0.f;
#pragma unroll
            for (int o = 0; o < 8; ++o)
                acc[o] = fmaf(w[o * 27 + ci * 9 + t], xv, acc[o]);
        }
    }

    float res[8];
    float* ob = out + (size_t)b * 8 * HW + pix;
#pragma unroll
    for (int o = 0; o < 8; ++o) {
        res[o] = fmaxf(acc[o], 0.f);
        ob[(size_t)o * HW] = res[o];
    }

    __shared__ float ls[16];
    stats_accum<8>(res, sacc, ls, tid);
}

// ---------------------------------------------------------------------------
// Generic NCHW 3x3 conv, inline input-BN, dot2 inner product.
// wp layout [(t*(CIN/2)+cp)][COUT] h2. BN coefs stashed in LDS.
// ---------------------------------------------------------------------------
template<int CIN, int COUT, bool RELU, bool STATS>
__global__ __launch_bounds__(256, 4) void convn_k(
    const float* __restrict__ x, const h2* __restrict__ wp,
    const float* __restrict__ bias, const float* __restrict__ st,
    const float* __restrict__ gg, const float* __restrict__ bb,
    float* __restrict__ out, float* __restrict__ sacc)
{
    const int tid = threadIdx.x;
    const int pix = blockIdx.x * 256 + tid;
    const int b   = blockIdx.y;
    const int h   = pix >> 6, ww = pix & 63;

    __shared__ float lsa[CIN], lsc[CIN];
    if (tid < CIN) {
        const float mean = st[tid], rstd = st[CIN + tid];
        lsa[tid] = gg[tid] * rstd;
        lsc[tid] = bb[tid] - gg[tid] * mean * rstd;
    }
    __syncthreads();

    int  tpix[9];
    bool tok[9];
#pragma unroll
    for (int t = 0; t < 9; ++t) {
        const int yy = h + t / 3 - 1, xx = ww + t % 3 - 1;
        tok[t]  = (yy >= 0) && (yy < 64) && (xx >= 0) && (xx < 64);
        tpix[t] = min(max(yy, 0), 63) * 64 + min(max(xx, 0), 63);
    }

    float acc[COUT];
#pragma unroll
    for (int o = 0; o < COUT; ++o) acc[o] = bias[o];

    const float* xb = x + (size_t)b * CIN * HW;

#pragma unroll
    for (int t = 0; t < 9; ++t) {
        const float* xq = xb + tpix[t];
        const bool ok = tok[t];
#pragma unroll
        for (int cp = 0; cp < CIN / 2; ++cp) {
            const int c = 2 * cp;
            const float x0 = xq[(size_t)c * HW];
            const float x1 = xq[(size_t)(c + 1) * HW];
            const float v0 = ok ? fmaf(lsa[c],     x0, lsc[c])     : 0.f;
            const float v1 = ok ? fmaf(lsa[c + 1], x1, lsc[c + 1]) : 0.f;
            const h2 val2 = __builtin_amdgcn_cvt_pkrtz(v0, v1);
            const h2* wrow = wp + (t * (CIN / 2) + cp) * COUT;
#pragma unroll
            for (int o = 0; o < COUT; ++o)
                acc[o] = __builtin_amdgcn_fdot2(val2, wrow[o], acc[o], false);
        }
    }

    float res[COUT];
    float* ob = out + (size_t)b * COUT * HW + pix;
#pragma unroll
    for (int o = 0; o < COUT; ++o) {
        res[o] = RELU ? fmaxf(acc[o], 0.f) : acc[o];
        ob[(size_t)o * HW] = res[o];
    }

    if (STATS) {
        __shared__ float ls[2 * COUT];
        stats_accum<COUT>(res, sacc, ls, tid);
    }
}

// ---------------------------------------------------------------------------
// Modulated deformable conv 3x3 (DG=2), NCHW, inline input-BN, dot2 inner.
// wp layout [(k*(CIN/2)+cglob/2)][O] h2 (global channel pairs per tap).
// ---------------------------------------------------------------------------
template<int CG, int O, bool STATS>
__global__ __launch_bounds__(256, 4) void deform_k(
    const float* __restrict__ x, const float* __restrict__ om,
    const h2* __restrict__ wp, const float* __restrict__ bias,
    const float* __restrict__ st, const float* __restrict__ gg,
    const float* __restrict__ bb,
    float* __restrict__ out, float* __restrict__ sacc)
{
    constexpr int CIN = 2 * CG;
    const int tid = threadIdx.x;
    const int pix = blockIdx.x * 256 + tid;
    const int b   = blockIdx.y;
    const int h   = pix >> 6, ww = pix & 63;

    __shared__ float lsa[CIN], lsc[CIN];
    if (tid < CIN) {
        const float mean = st[tid], rstd = st[CIN + tid];
        lsa[tid] = gg[tid] * rstd;
        lsc[tid] = bb[tid] - gg[tid] * mean * rstd;
    }
    __syncthreads();

    float acc[O];
#pragma unroll
    for (int o = 0; o < O; ++o) acc[o] = bias[o];

    const float* omb = om + (size_t)b * 54 * HW + pix;
    const float* xb  = x + (size_t)b * CIN * HW;

    for (int g = 0; g < 2; ++g) {
#pragma unroll
        for (int k = 0; k < 9; ++k) {
            const int gk = g * 9 + k;
            const float offy = omb[(size_t)gk * HW];
            const float offx = omb[(size_t)(18 + gk) * HW];
            const float mraw = omb[(size_t)(36 + gk) * HW];
            const float msk  = 1.f / (1.f + __expf(-mraw));

            const float py = (float)(h + k / 3 - 1) + offy;
            const float px = (float)(ww + k % 3 - 1) + offx;
            const float y0f = floorf(py), x0f = floorf(px);
            const float ly = py - y0f, lx = px - x0f;
            const int y0 = (int)y0f, x0 = (int)x0f;
            const int y1 = y0 + 1,  x1 = x0 + 1;

            const bool y0ok = (y0 >= 0) && (y0 < 64);
            const bool y1ok = (y1 >= 0) && (y1 < 64);
            const bool x0ok = (x0 >= 0) && (x0 < 64);
            const bool x1ok = (x1 >= 0) && (x1 < 64);

            float w00 = (1.f-ly)*(1.f-lx)*msk; if (!(y0ok&&x0ok)) w00 = 0.f;
            float w01 = (1.f-ly)*lx      *msk; if (!(y0ok&&x1ok)) w01 = 0.f;
            float w10 = ly*(1.f-lx)      *msk; if (!(y1ok&&x0ok)) w10 = 0.f;
            float w11 = ly*lx            *msk; if (!(y1ok&&x1ok)) w11 = 0.f;
            const float wsum = w00 + w01 + w10 + w11;

            const int i00 = min(max(y0,0),63) * 64 + min(max(x0,0),63);
            const int dx  = (min(max(x1,0),63) - min(max(x0,0),63));
            const int dy  = (min(max(y1,0),63) - min(max(y0,0),63)) * 64;

#pragma unroll
            for (int cp = 0; cp < CG / 2; ++cp) {
                const int c = g * CG + 2 * cp;
                const float* xp0 = xb + (size_t)c * HW + i00;
                const float* xp1 = xp0 + HW;

                const float a00 = xp0[0],  a01 = xp0[dx];
                const float a10 = xp0[dy], a11 = xp0[dy + dx];
                const float b00 = xp1[0],  b01 = xp1[dx];
                const float b10 = xp1[dy], b11 = xp1[dy + dx];

                const float g0 = w00*a00 + w01*a01 + w10*a10 + w11*a11;
                const float g1 = w00*b00 + w01*b01 + w10*b10 + w11*b11;
                const float v0 = fmaf(lsa[c],     g0, lsc[c]     * wsum);
                const float v1 = fmaf(lsa[c + 1], g1, lsc[c + 1] * wsum);
                const h2 val2 = __builtin_amdgcn_cvt_pkrtz(v0, v1);

                const h2* wrow = wp + (k * (CIN / 2) + (c >> 1)) * O;
#pragma unroll
                for (int o = 0; o < O; ++o)
                    acc[o] = __builtin_amdgcn_fdot2(val2, wrow[o], acc[o], false);
            }
        }
    }

    float res[O];
    float* ob = out + (size_t)b * O * HW + pix;
#pragma unroll
    for (int o = 0; o < O; ++o) {
        res[o] = fmaxf(acc[o], 0.f);
        ob[(size_t)o * HW] = res[o];
    }

    if (STATS) {
        __shared__ float ls[2 * O];
        stats_accum<O>(res, sacc, ls, tid);
    }
}

// ---------------------------------------------------------------------------
// BN apply in place on em (NCHW 64ch): 4,194,304 float4 -> 16384 blocks.
// ---------------------------------------------------------------------------
__global__ __launch_bounds__(256) void bn_apply4_k(
    float* __restrict__ y, const float* __restrict__ st,
    const float* __restrict__ gg, const float* __restrict__ bb)
{
    const size_t i4 = (size_t)blockIdx.x * 256 + threadIdx.x;
    const int c = (int)((i4 >> 10) & 63);
    const float m = st[c], r = st[64 + c];
    const float a = gg[c] * r, cc = bb[c] - gg[c] * m * r;
    float4 v = ((float4*)y)[i4];
    v.x = a*v.x + cc; v.y = a*v.y + cc; v.z = a*v.z + cc; v.w = a*v.w + cc;
    ((float4*)y)[i4] = v;
}

// ---------------------------------------------------------------------------
// Quadrant avg-pool: grid (B, C), one wave per quadrant.
// ---------------------------------------------------------------------------
__global__ __launch_bounds__(256) void pool_k(
    const float* __restrict__ em, float* __restrict__ pooled)
{
    const int b = blockIdx.x, c = blockIdx.y, t = threadIdx.x;
    const int q = t >> 6, l = t & 63;
    const float* p = em + ((size_t)b * 64 + c) * HW + (q >> 1) * 32 * W_ + (q & 1) * 32;
    float s = 0.f;
    for (int i = l; i < 1024; i += 64) {
        const int yy = i >> 5, xx = i & 31;
        s += p[yy * W_ + xx];
    }
    for (int off = 32; off; off >>= 1) s += __shfl_down(s, off);
    if (l == 0) pooled[b * 256 + c * 4 + q] = s * (1.f / 1024.f);
}

// ---------------------------------------------------------------------------
// FC(256->10) + softmax. One block (64 threads) per image.
// ---------------------------------------------------------------------------
__global__ __launch_bounds__(64) void fc_k(
    const float* __restrict__ pooled, const float* __restrict__ fcw,
    const float* __restrict__ fcb, float* __restrict__ out)
{
    const int b = blockIdx.x, t = threadIdx.x;
    __shared__ float logits[10];
    if (t < 10) {
        float l = fcb[t];
        const float* p = pooled + b * 256;
        for (int j = 0; j < 256; ++j) l += fcw[t * 256 + j] * p[j];
        logits[t] = l;
    }
    __syncthreads();
    if (t == 0) {
        float mx = logits[0];
        for (int i = 1; i < 10; ++i) mx = fmaxf(mx, logits[i]);
        float e[10]; float sum = 0.f;
        for (int i = 0; i < 10; ++i) { e[i] = __expf(logits[i] - mx); sum += e[i]; }
        const float inv = 1.f / sum;
        for (int i = 0; i < 10; ++i) out[b * 10 + i] = e[i] * inv;
    }
}

// ---------------------------------------------------------------------------
extern "C" void kernel_launch(void* const* d_in, const int* in_sizes, int n_in,
                              void* d_out, int out_size, void* d_ws, size_t ws_size,
                              hipStream_t stream)
{
    const float* x       = (const float*)d_in[0];
    const float* conv1_w = (const float*)d_in[1];
    const float* bn1_g   = (const float*)d_in[2];
    const float* bn1_b   = (const float*)d_in[3];
    const float* conv2_w = (const float*)d_in[4];
    const float* conv2_b = (const float*)d_in[5];
    const float* bn2_g   = (const float*)d_in[6];
    const float* bn2_b   = (const float*)d_in[7];
    const float* off1_w  = (const float*)d_in[8];
    const float* off1_b  = (const float*)d_in[9];
    const float* d1_w    = (const float*)d_in[10];
    const float* d1_b    = (const float*)d_in[11];
    const float* bn3_g   = (const float*)d_in[12];
    const float* bn3_b   = (const float*)d_in[13];
    const float* off2_w  = (const float*)d_in[14];
    const float* off2_b  = (const float*)d_in[15];
    const float* d2_w    = (const float*)d_in[16];
    const float* d2_b    = (const float*)d_in[17];
    const float* bn4_g   = (const float*)d_in[18];
    const float* bn4_b   = (const float*)d_in[19];
    const float* fc_w    = (const float*)d_in[20];
    const float* fc_b    = (const float*)d_in[21];

    // Workspace (floats), all NCHW. ~119.9 MB.
    float* ws = (float*)d_ws;
    float* Bb = ws;                    // [B][20][HW]  5,242,880
    float* D  = ws + 5242880;          // [B][40][HW] 10,485,760
    float* C  = ws + 15728640;         // om [B][54][HW] 14,155,776
    float* A  = C;                     // [B][8][HW] (aliases C; dead before off1)
    float* sm = ws + 29884416;
    float* s1 = sm,        *s2 = sm + 16,  *s3 = sm + 56,  *s4 = sm + 136; // sums (264)
    float* st1 = sm + 264, *st2 = sm + 280, *st3 = sm + 320, *st4 = sm + 400;
    float* pooled = sm + 528;          // 16384 (end 16912)
    // packed h2 weights (1 float slot each)
    h2* c2P = (h2*)(sm + 16912);       //  720
    h2* o1P = (h2*)(sm + 17632);       // 4860
    h2* o2P = (h2*)(sm + 22492);       // 9720
    h2* d1P = (h2*)(sm + 32212);       // 3600
    h2* d2P = (h2*)(sm + 35812);       // 11520 (end 47332)

    float* outp = (float*)d_out;
    float* em   = outp + 640;          // NCHW [64][64][64][64]

    const dim3 blk(256);
    const dim3 gpix(16, B_);

    (void)hipMemsetAsync(sm, 0, 264 * sizeof(float), stream);

    wpack_k<<<(720   + 255)/256, blk, 0, stream>>>(conv2_w, c2P, 20, 8);
    wpack_k<<<(4860  + 255)/256, blk, 0, stream>>>(off1_w,  o1P, 54, 20);
    wpack_k<<<(9720  + 255)/256, blk, 0, stream>>>(off2_w,  o2P, 54, 40);
    wpack_k<<<(3600  + 255)/256, blk, 0, stream>>>(d1_w,    d1P, 40, 20);
    wpack_k<<<(11520 + 255)/256, blk, 0, stream>>>(d2_w,    d2P, 64, 40);

    // layer 1: conv(3->8)+relu -> A + stats1
    conv1_k<<<gpix, blk, 0, stream>>>(x, conv1_w, A, s1);
    bn_fin_k<8><<<1, 64, 0, stream>>>(s1, st1);

    // layer 2: conv(8->20)+bias+relu, BN1 inline -> Bb + stats2
    convn_k<8, 20, true, true><<<gpix, blk, 0, stream>>>(
        A, c2P, conv2_b, st1, bn1_g, bn1_b, Bb, s2);
    bn_fin_k<20><<<1, 64, 0, stream>>>(s2, st2);

    // deform block 1
    convn_k<20, 54, false, false><<<gpix, blk, 0, stream>>>(
        Bb, o1P, off1_b, st2, bn2_g, bn2_b, C, nullptr);
    deform_k<10, 40, true><<<gpix, blk, 0, stream>>>(
        Bb, C, d1P, d1_b, st2, bn2_g, bn2_b, D, s3);
    bn_fin_k<40><<<1, 64, 0, stream>>>(s3, st3);

    // deform block 2
    convn_k<40, 54, false, false><<<gpix, blk, 0, stream>>>(
        D, o2P, off2_b, st3, bn3_g, bn3_b, C, nullptr);
    deform_k<20, 64, true><<<gpix, blk, 0, stream>>>(
        D, C, d2P, d2_b, st3, bn3_g, bn3_b, em, s4);
    bn_fin_k<64><<<1, 64, 0, stream>>>(s4, st4);

    // layer-4 BN in place on em
    bn_apply4_k<<<16384, blk, 0, stream>>>(em, st4, bn4_g, bn4_b);

    // head
    pool_k<<<dim3(B_, 64), blk, 0, stream>>>(em, pooled);
    fc_k<<<B_, 64, 0, stream>>>(pooled, fc_w, fc_b, outp);
}

// Round 10
// 869.860 us; speedup vs baseline: 2.8529x; 2.8529x over previous
//
#include <hip/hip_runtime.h>
#include <math.h>

#define B_  64
#define H_  64
#define W_  64
#define HW  4096   // H_*W_
#define NPIX 262144.0f  // B_*HW

// ---------------------------------------------------------------------------
// Weight transpose: w[O][CK] -> wT[CK][O]
// ---------------------------------------------------------------------------
__global__ __launch_bounds__(256) void wtr_k(
    const float* __restrict__ w, float* __restrict__ wT, int O, int CK)
{
    const int i = blockIdx.x * 256 + threadIdx.x;
    if (i < O * CK) {
        const int o = i / CK, ck = i - o * CK;
        wT[ck * O + o] = w[i];
    }
}

// ---------------------------------------------------------------------------
// Fused per-block BN stats accumulation (sum, sumsq per channel).
// Wave shuffle-reduce -> LDS -> one global atomicAdd per (block, channel).
// ---------------------------------------------------------------------------
template<int CT>
__device__ __forceinline__ void stats_accum(
    const float* res, float* sacc, float* ls, int tid)
{
    if (tid < 2 * CT) ls[tid] = 0.f;
    __syncthreads();
#pragma unroll
    for (int o = 0; o < CT; ++o) {
        float s = res[o], s2 = res[o] * res[o];
        for (int off = 32; off; off >>= 1) {
            s  += __shfl_down(s,  off);
            s2 += __shfl_down(s2, off);
        }
        if ((tid & 63) == 0) {
            atomicAdd(&ls[2 * o],     s);
            atomicAdd(&ls[2 * o + 1], s2);
        }
    }
    __syncthreads();
    if (tid < 2 * CT) atomicAdd(&sacc[tid], ls[tid]);
}

// ---------------------------------------------------------------------------
// BN finalize: sums -> mean/rstd.
// ---------------------------------------------------------------------------
template<int C>
__global__ __launch_bounds__(64) void bn_fin_k(
    const float* __restrict__ sacc, float* __restrict__ st)
{
    const int t = threadIdx.x;
    if (t < C) {
        const float mean = sacc[2 * t] / NPIX;
        const float var  = sacc[2 * t + 1] / NPIX - mean * mean;
        st[t]     = mean;
        st[C + t] = rsqrtf(var + 1e-5f);
    }
}

// ---------------------------------------------------------------------------
// conv1: 3x3 conv (3->8) + ReLU, NCHW in/out, fused stats.
// ---------------------------------------------------------------------------
__global__ __launch_bounds__(256) void conv1_k(
    const float* __restrict__ x, const float* __restrict__ w,
    float* __restrict__ out, float* __restrict__ sacc)
{
    const int tid = threadIdx.x;
    const int pix = blockIdx.x * 256 + tid;
    const int b   = blockIdx.y;
    const int h   = pix >> 6, ww = pix & 63;

    float acc[8];
#pragma unroll
    for (int o = 0; o < 8; ++o) acc[o] = 0.f;

#pragma unroll
    for (int ci = 0; ci < 3; ++ci) {
        const float* xp = x + ((size_t)b * 3 + ci) * HW;
#pragma unroll
        for (int t = 0; t < 9; ++t) {
            const int yy = h + t / 3 - 1, xx = ww + t % 3 - 1;
            const bool ok = (yy >= 0) && (yy < 64) && (xx >= 0) && (xx < 64);
            const float xv = ok ? xp[min(max(yy,0),63) * 64 + min(max(xx,0),63)] : 0.f;
#pragma unroll
            for (int o = 0; o < 8; ++o)
                acc[o] = fmaf(w[o * 27 + ci * 9 + t], xv, acc[o]);
        }
    }

    float res[8];
    float* ob = out + (size_t)b * 8 * HW + pix;
#pragma unroll
    for (int o = 0; o < 8; ++o) {
        res[o] = fmaxf(acc[o], 0.f);
        ob[(size_t)o * HW] = res[o];
    }

    __shared__ float ls[16];
    stats_accum<8>(res, sacc, ls, tid);
}

// ---------------------------------------------------------------------------
// Generic NCHW 3x3 conv, inline input-BN (a*x+c, OOB taps 0), bias,
// optional ReLU/stats. wT layout [ci*9+t][COUT] (o contiguous, uniform ->
// SGPR weight path). All COUT accs in registers (AGPR-backed).
// waves_per_eu(1,4): allow up to 128+ VGPRs -> prefetch headroom; grid only
// sustains 16 waves/CU anyway (1 thread = 1 pixel).
// ---------------------------------------------------------------------------
template<int CIN, int COUT, bool RELU, bool STATS>
__global__ __launch_bounds__(256) __attribute__((amdgpu_waves_per_eu(1, 4)))
void convn_k(
    const float* __restrict__ x, const float* __restrict__ wT,
    const float* __restrict__ bias, const float* __restrict__ st,
    const float* __restrict__ gg, const float* __restrict__ bb,
    float* __restrict__ out, float* __restrict__ sacc)
{
    const int tid = threadIdx.x;
    const int pix = blockIdx.x * 256 + tid;
    const int b   = blockIdx.y;
    const int h   = pix >> 6, ww = pix & 63;

    int  tpix[9];
    bool tok[9];
#pragma unroll
    for (int t = 0; t < 9; ++t) {
        const int yy = h + t / 3 - 1, xx = ww + t % 3 - 1;
        tok[t]  = (yy >= 0) && (yy < 64) && (xx >= 0) && (xx < 64);
        tpix[t] = min(max(yy, 0), 63) * 64 + min(max(xx, 0), 63);
    }

    float acc[COUT];
#pragma unroll
    for (int o = 0; o < COUT; ++o) acc[o] = bias[o];

    const float* xb = x + (size_t)b * CIN * HW;

    for (int ci = 0; ci < CIN; ++ci) {
        const float mean = st[ci], rstd = st[CIN + ci];
        const float a  = gg[ci] * rstd;
        const float cc = bb[ci] - gg[ci] * mean * rstd;
        const float* xp = xb + (size_t)ci * HW;

        float xv[9];
#pragma unroll
        for (int t = 0; t < 9; ++t)
            xv[t] = tok[t] ? fmaf(a, xp[tpix[t]], cc) : 0.f;

#pragma unroll
        for (int t = 0; t < 9; ++t) {
            const float* wp = wT + (ci * 9 + t) * COUT;
#pragma unroll
            for (int o = 0; o < COUT; ++o)
                acc[o] = fmaf(wp[o], xv[t], acc[o]);
        }
    }

    float res[COUT];
    float* ob = out + (size_t)b * COUT * HW + pix;
#pragma unroll
    for (int o = 0; o < COUT; ++o) {
        res[o] = RELU ? fmaxf(acc[o], 0.f) : acc[o];
        ob[(size_t)o * HW] = res[o];
    }

    if (STATS) {
        __shared__ float ls[2 * COUT];
        stats_accum<COUT>(res, sacc, ls, tid);
    }
}

// ---------------------------------------------------------------------------
// Modulated deformable conv 3x3 (DG=2), NCHW x / om / out, inline input-BN,
// wT layout [(g*CG+c)*9+k][O]. bias+ReLU, fused stats. No z-split.
// Channel sub-chunks of VL: 4*VL corner loads issued before blend+FMA burst.
// ---------------------------------------------------------------------------
template<int CG, int O, int VL, bool STATS>
__global__ __launch_bounds__(256) __attribute__((amdgpu_waves_per_eu(1, 4)))
void deform_k(
    const float* __restrict__ x, const float* __restrict__ om,
    const float* __restrict__ wT, const float* __restrict__ bias,
    const float* __restrict__ st, const float* __restrict__ gg,
    const float* __restrict__ bb,
    float* __restrict__ out, float* __restrict__ sacc)
{
    constexpr int CIN = 2 * CG;
    const int tid = threadIdx.x;
    const int pix = blockIdx.x * 256 + tid;
    const int b   = blockIdx.y;
    const int h   = pix >> 6, ww = pix & 63;

    float acc[O];
#pragma unroll
    for (int o = 0; o < O; ++o) acc[o] = bias[o];

    const float* omb = om + (size_t)b * 54 * HW + pix;
    const float* xb  = x + (size_t)b * CIN * HW;

    for (int g = 0; g < 2; ++g) {
#pragma unroll
        for (int k = 0; k < 9; ++k) {
            const int gk = g * 9 + k;
            const float offy = omb[(size_t)gk * HW];
            const float offx = omb[(size_t)(18 + gk) * HW];
            const float mraw = omb[(size_t)(36 + gk) * HW];
            const float msk  = 1.f / (1.f + __expf(-mraw));

            const float py = (float)(h + k / 3 - 1) + offy;
            const float px = (float)(ww + k % 3 - 1) + offx;
            const float y0f = floorf(py), x0f = floorf(px);
            const float ly = py - y0f, lx = px - x0f;
            const int y0 = (int)y0f, x0 = (int)x0f;
            const int y1 = y0 + 1,  x1 = x0 + 1;

            const bool y0ok = (y0 >= 0) && (y0 < 64);
            const bool y1ok = (y1 >= 0) && (y1 < 64);
            const bool x0ok = (x0 >= 0) && (x0 < 64);
            const bool x1ok = (x1 >= 0) && (x1 < 64);

            float w00 = (1.f-ly)*(1.f-lx)*msk; if (!(y0ok&&x0ok)) w00 = 0.f;
            float w01 = (1.f-ly)*lx      *msk; if (!(y0ok&&x1ok)) w01 = 0.f;
            float w10 = ly*(1.f-lx)      *msk; if (!(y1ok&&x0ok)) w10 = 0.f;
            float w11 = ly*lx            *msk; if (!(y1ok&&x1ok)) w11 = 0.f;
            const float wsum = w00 + w01 + w10 + w11;

            const int i00 = min(max(y0,0),63) * 64 + min(max(x0,0),63);
            const int dx  = (min(max(x1,0),63) - min(max(x0,0),63));
            const int dy  = (min(max(y1,0),63) - min(max(y0,0),63)) * 64;

            // channel sub-chunks: issue 4*VL independent loads, then FMA burst
            for (int cb = 0; cb < CG / VL; ++cb) {
                const int c0 = g * CG + cb * VL;

                float v00[VL], v01[VL], v10[VL], v11[VL];
#pragma unroll
                for (int j = 0; j < VL; ++j) {
                    const float* xp = xb + (size_t)(c0 + j) * HW + i00;
                    v00[j] = xp[0];
                    v01[j] = xp[dx];
                    v10[j] = xp[dy];
                    v11[j] = xp[dy + dx];
                }

                float val[VL];
#pragma unroll
                for (int j = 0; j < VL; ++j) {
                    const float mean = st[c0 + j], rstd = st[CIN + c0 + j];
                    const float a  = gg[c0 + j] * rstd;
                    const float cc = bb[c0 + j] - gg[c0 + j] * mean * rstd;
                    const float gath = w00*v00[j] + w01*v01[j] +
                                       w10*v10[j] + w11*v11[j];
                    val[j] = fmaf(a, gath, cc * wsum);
                }

                const float* wp0 = wT + ((c0 + 0) * 9 + k) * O;
                const float* wp1 = wT + ((c0 + 1) * 9 + k) * O;
#pragma unroll
                for (int o = 0; o < O; ++o) {
                    float t = acc[o];
                    t = fmaf(wp0[o], val[0], t);
                    t = fmaf(wp1[o], val[1], t);
                    if (VL == 4) {
                        t = fmaf(wp1[O * 9 + o], val[2], t);      // c0+2
                        t = fmaf(wp1[2 * O * 9 + o], val[3], t);  // c0+3
                    }
                    acc[o] = t;
                }
            }
        }
    }

    float res[O];
    float* ob = out + (size_t)b * O * HW + pix;
#pragma unroll
    for (int o = 0; o < O; ++o) {
        res[o] = fmaxf(acc[o], 0.f);
        ob[(size_t)o * HW] = res[o];
    }

    if (STATS) {
        __shared__ float ls[2 * O];
        stats_accum<O>(res, sacc, ls, tid);
    }
}

// ---------------------------------------------------------------------------
// BN apply in place on em (NCHW 64ch): 4,194,304 float4 -> 16384 blocks.
// ---------------------------------------------------------------------------
__global__ __launch_bounds__(256) void bn_apply4_k(
    float* __restrict__ y, const float* __restrict__ st,
    const float* __restrict__ gg, const float* __restrict__ bb)
{
    const size_t i4 = (size_t)blockIdx.x * 256 + threadIdx.x;
    const int c = (int)((i4 >> 10) & 63);
    const float m = st[c], r = st[64 + c];
    const float a = gg[c] * r, cc = bb[c] - gg[c] * m * r;
    float4 v = ((float4*)y)[i4];
    v.x = a*v.x + cc; v.y = a*v.y + cc; v.z = a*v.z + cc; v.w = a*v.w + cc;
    ((float4*)y)[i4] = v;
}

// ---------------------------------------------------------------------------
// Quadrant avg-pool: grid (B, C), one wave per quadrant.
// ---------------------------------------------------------------------------
__global__ __launch_bounds__(256) void pool_k(
    const float* __restrict__ em, float* __restrict__ pooled)
{
    const int b = blockIdx.x, c = blockIdx.y, t = threadIdx.x;
    const int q = t >> 6, l = t & 63;
    const float* p = em + ((size_t)b * 64 + c) * HW + (q >> 1) * 32 * W_ + (q & 1) * 32;
    float s = 0.f;
    for (int i = l; i < 1024; i += 64) {
        const int yy = i >> 5, xx = i & 31;
        s += p[yy * W_ + xx];
    }
    for (int off = 32; off; off >>= 1) s += __shfl_down(s, off);
    if (l == 0) pooled[b * 256 + c * 4 + q] = s * (1.f / 1024.f);
}

// ---------------------------------------------------------------------------
// FC(256->10) + softmax. One block (64 threads) per image.
// ---------------------------------------------------------------------------
__global__ __launch_bounds__(64) void fc_k(
    const float* __restrict__ pooled, const float* __restrict__ fcw,
    const float* __restrict__ fcb, float* __restrict__ out)
{
    const int b = blockIdx.x, t = threadIdx.x;
    __shared__ float logits[10];
    if (t < 10) {
        float l = fcb[t];
        const float* p = pooled + b * 256;
        for (int j = 0; j < 256; ++j) l += fcw[t * 256 + j] * p[j];
        logits[t] = l;
    }
    __syncthreads();
    if (t == 0) {
        float mx = logits[0];
        for (int i = 1; i < 10; ++i) mx = fmaxf(mx, logits[i]);
        float e[10]; float sum = 0.f;
        for (int i = 0; i < 10; ++i) { e[i] = __expf(logits[i] - mx); sum += e[i]; }
        const float inv = 1.f / sum;
        for (int i = 0; i < 10; ++i) out[b * 10 + i] = e[i] * inv;
    }
}

// ---------------------------------------------------------------------------
extern "C" void kernel_launch(void* const* d_in, const int* in_sizes, int n_in,
                              void* d_out, int out_size, void* d_ws, size_t ws_size,
                              hipStream_t stream)
{
    const float* x       = (const float*)d_in[0];
    const float* conv1_w = (const float*)d_in[1];
    const float* bn1_g   = (const float*)d_in[2];
    const float* bn1_b   = (const float*)d_in[3];
    const float* conv2_w = (const float*)d_in[4];
    const float* conv2_b = (const float*)d_in[5];
    const float* bn2_g   = (const float*)d_in[6];
    const float* bn2_b   = (const float*)d_in[7];
    const float* off1_w  = (const float*)d_in[8];
    const float* off1_b  = (const float*)d_in[9];
    const float* d1_w    = (const float*)d_in[10];
    const float* d1_b    = (const float*)d_in[11];
    const float* bn3_g   = (const float*)d_in[12];
    const float* bn3_b   = (const float*)d_in[13];
    const float* off2_w  = (const float*)d_in[14];
    const float* off2_b  = (const float*)d_in[15];
    const float* d2_w    = (const float*)d_in[16];
    const float* d2_b    = (const float*)d_in[17];
    const float* bn4_g   = (const float*)d_in[18];
    const float* bn4_b   = (const float*)d_in[19];
    const float* fc_w    = (const float*)d_in[20];
    const float* fc_b    = (const float*)d_in[21];

    // Workspace (floats), all NCHW. ~119.9 MB.
    float* ws = (float*)d_ws;
    float* Bb = ws;                    // [B][20][HW]  5,242,880
    float* D  = ws + 5242880;          // [B][40][HW] 10,485,760
    float* C  = ws + 15728640;         // om [B][54][HW] 14,155,776
    float* A  = C;                     // [B][8][HW] (aliases C; dead before off1)
    float* sm = ws + 29884416;
    float* s1 = sm,        *s2 = sm + 16,  *s3 = sm + 56,  *s4 = sm + 136; // sums (264)
    float* st1 = sm + 264, *st2 = sm + 280, *st3 = sm + 320, *st4 = sm + 400;
    float* pooled = sm + 528;          // 16384
    float* c2T = sm + 16912;           // [72][20]    1,440
    float* o1T = sm + 18352;           // [180][54]   9,720
    float* o2T = sm + 28072;           // [360][54]  19,440
    float* d1T = sm + 47512;           // [180][40]   7,200
    float* d2T = sm + 54712;           // [360][64]  23,040

    float* outp = (float*)d_out;
    float* em   = outp + 640;          // NCHW [64][64][64][64]

    const dim3 blk(256);
    const dim3 gpix(16, B_);

    (void)hipMemsetAsync(sm, 0, 264 * sizeof(float), stream);

    wtr_k<<<(20*72  + 255)/256, blk, 0, stream>>>(conv2_w, c2T, 20, 72);
    wtr_k<<<(54*180 + 255)/256, blk, 0, stream>>>(off1_w,  o1T, 54, 180);
    wtr_k<<<(54*360 + 255)/256, blk, 0, stream>>>(off2_w,  o2T, 54, 360);
    wtr_k<<<(40*180 + 255)/256, blk, 0, stream>>>(d1_w,    d1T, 40, 180);
    wtr_k<<<(64*360 + 255)/256, blk, 0, stream>>>(d2_w,    d2T, 64, 360);

    // layer 1: conv(3->8)+relu -> A + stats1
    conv1_k<<<gpix, blk, 0, stream>>>(x, conv1_w, A, s1);
    bn_fin_k<8><<<1, 64, 0, stream>>>(s1, st1);

    // layer 2: conv(8->20)+bias+relu, BN1 inline -> Bb + stats2
    convn_k<8, 20, true, true><<<gpix, blk, 0, stream>>>(
        A, c2T, conv2_b, st1, bn1_g, bn1_b, Bb, s2);
    bn_fin_k<20><<<1, 64, 0, stream>>>(s2, st2);

    // deform block 1
    convn_k<20, 54, false, false><<<gpix, blk, 0, stream>>>(
        Bb, o1T, off1_b, st2, bn2_g, bn2_b, C, nullptr);
    deform_k<10, 40, 2, true><<<gpix, blk, 0, stream>>>(
        Bb, C, d1T, d1_b, st2, bn2_g, bn2_b, D, s3);
    bn_fin_k<40><<<1, 64, 0, stream>>>(s3, st3);

    // deform block 2
    convn_k<40, 54, false, false><<<gpix, blk, 0, stream>>>(
        D, o2T, off2_b, st3, bn3_g, bn3_b, C, nullptr);
    deform_k<20, 64, 4, true><<<gpix, blk, 0, stream>>>(
        D, C, d2T, d2_b, st3, bn3_g, bn3_b, em, s4);
    bn_fin_k<64><<<1, 64, 0, stream>>>(s4, st4);

    // layer-4 BN in place on em
    bn_apply4_k<<<16384, blk, 0, stream>>>(em, st4, bn4_g, bn4_b);

    // head
    pool_k<<<dim3(B_, 64), blk, 0, stream>>>(em, pooled);
    fc_k<<<B_, 64, 0, stream>>>(pooled, fc_w, fc_b, outp);
}